// Round 15
// baseline (204.551 us; speedup 1.0000x reference)
//
#include <hip/hip_runtime.h>
#include <cstdint>
#include <cstddef>

// Problem constants (SparseLinear: B=4096, IN=4096, OUT=4096, NNZ=1677722)
#define IN_F  4096
#define OUT_F 4096
#define BATCH 4096

typedef __bf16 bf16_t;
typedef __bf16 bf16x8 __attribute__((ext_vector_type(8)));
typedef float  f32x16 __attribute__((ext_vector_type(16)));

// ---------------------------------------------------------------------------
// f32 -> bf16 round-to-nearest-even (bit trick, deterministic)
// ---------------------------------------------------------------------------
__device__ __forceinline__ unsigned short f32_to_bf16_rne(float f) {
  union { float f; unsigned int u; } v;
  v.f = f;
  unsigned int u = v.u;
  return (unsigned short)((u + 0x7FFFu + ((u >> 16) & 1u)) >> 16);
}

__device__ __forceinline__ uint4 cvt8(float4 a, float4 b) {
  uint4 o;
  o.x = (unsigned)f32_to_bf16_rne(a.x) | ((unsigned)f32_to_bf16_rne(a.y) << 16);
  o.y = (unsigned)f32_to_bf16_rne(a.z) | ((unsigned)f32_to_bf16_rne(a.w) << 16);
  o.z = (unsigned)f32_to_bf16_rne(b.x) | ((unsigned)f32_to_bf16_rne(b.y) << 16);
  o.w = (unsigned)f32_to_bf16_rne(b.z) | ((unsigned)f32_to_bf16_rne(b.w) << 16);
  return o;
}

// ---------------------------------------------------------------------------
// Fused: scatter (packed-bf16 atomics, issued FIRST — R14: partial overlap
// with the BW-bound cvt, tail is fabric-RMW-bound ~65us) + cvt x -> bf16.
// mask is int32 on device (R1). Duplicates sum (coalesce semantics).
// ---------------------------------------------------------------------------
#define XUNITS ((BATCH * IN_F) / 8)   // 8-elem units of x (2097152)

__global__ __launch_bounds__(256) void scatter_cvtx(
    const float* __restrict__ w, const int* __restrict__ rows,
    const int* __restrict__ cols, const int* __restrict__ mask,
    unsigned* __restrict__ Wpk, int nnz,
    const float4* __restrict__ xin, uint4* __restrict__ xbf) {
  const int total = XUNITS + nnz;
  for (int u = blockIdx.x * 256 + threadIdx.x; u < total;
       u += gridDim.x * 256) {
    if (u < nnz) {                      // atomics first (fire-and-forget)
      if (mask[u] != 0) {
        const unsigned h = f32_to_bf16_rne(w[u]);
        const size_t e = (size_t)rows[u] * IN_F + cols[u];
        const unsigned data = (e & 1) ? (h << 16) : h;
        unsigned* p = Wpk + (e >> 1);
        asm volatile("global_atomic_pk_add_bf16 %0, %1, off"
                     :: "v"(p), "v"(data) : "memory");
      }
    } else {                            // BW-bound cvt streams under them
      const int i = u - nnz;
      xbf[i] = cvt8(xin[2 * i], xin[2 * i + 1]);
    }
  }
}

// ---------------------------------------------------------------------------
// R15: 32x32x16-MFMA 256x256 GEMM, C = A @ Bm^T. Wave tile stays 128x64
// (acc = 4x2 f32x16 = 128 VGPR, no spill — R11's failure was the 128x128
// acc, NOT the 32x32 mappings, which R11 validated numerically).
// Gain: 32x32x16 pipe = 2382 TF vs 16x16x32's 2075 (m119/m06) -> MFMA term
// of the serial sum drops ~13%.
// LDS: [256 rows][64 k] bf16 = 128B rows, 4 buffers x 32KB (A0,B0,A1,B1).
// Bank algebra (128B rows): bank-group = (slot ^ s(row)) & 7 — row parity
// drops out (row*128 % 128B = 0). s(row) = (row>>1)&7 puts a 32-row x
// 2-slot b128 wave read at exactly 8 lanes/bank-group = minimum = 0
// conflicts (same criterion as R4's measured 0). Write side: thread tid
// (row tid>>3, phys slot tid&7) sources global chunk (tid&7)^s(row);
// s invariant under row+64/+128. Involution verified.
// Phase structure/ledger = R13 verbatim (B-hoist quadrants, 1 STAGE-pair
// per phase, VM(4)@ph4/ph8, peeled epilogue with VM(0)@ep4). Per phase:
// 4 (or 12 with B-hoist) ds_read_b128 + 8 MFMA of 32x32x16.
// ---------------------------------------------------------------------------
#define A0_B 0
#define B0_B 32768
#define A1_B 65536
#define B1_B 98304

#define STAGE(Xg, kpos, ldsbase, roff) do {                                    \
  __builtin_amdgcn_global_load_lds(                                            \
    (const __attribute__((address_space(1))) void*)((Xg) + (size_t)(srow + (roff)) * 4096 + (kpos) + schunk), \
    (__attribute__((address_space(3))) void*)(lds + (ldsbase) + (roff) * 128 + tid * 16), 16, 0, 0); \
  __builtin_amdgcn_global_load_lds(                                            \
    (const __attribute__((address_space(1))) void*)((Xg) + (size_t)(srow + (roff) + 64) * 4096 + (kpos) + schunk), \
    (__attribute__((address_space(3))) void*)(lds + (ldsbase) + (roff) * 128 + 8192 + tid * 16), 16, 0, 0); \
} while (0)

// B for the whole K64 tile: 2 N-frags x 4 k-steps (8 x ds_read_b128)
#define RDB(base) do {                                                         \
  _Pragma("unroll")                                                            \
  for (int ni = 0; ni < 2; ++ni)                                               \
    _Pragma("unroll")                                                          \
    for (int kk = 0; kk < 4; ++kk)                                             \
      b[ni][kk] = *(const bf16x8*)(lds + (base) + offB[ni][kk]);               \
} while (0)

// A for one 32-row quadrant: 4 k-steps (4 x ds_read_b128)
#define RDA(base, q) do {                                                      \
  _Pragma("unroll")                                                            \
  for (int kk = 0; kk < 4; ++kk)                                               \
    a[kk] = *(const bf16x8*)(lds + (base) + offA[q][kk]);                      \
} while (0)

// One quadrant x K64: 1M x 2N x 4K = 8 MFMA of 32x32x16 (2 acc chains)
#define MFMAQ(q) do {                                                          \
  _Pragma("unroll")                                                            \
  for (int kk = 0; kk < 4; ++kk)                                               \
    _Pragma("unroll")                                                          \
    for (int ni = 0; ni < 2; ++ni)                                             \
      acc[q][ni] = __builtin_amdgcn_mfma_f32_32x32x16_bf16(                    \
          a[kk], b[ni][kk], acc[q][ni], 0, 0, 0);                              \
} while (0)

#define BAR()   __builtin_amdgcn_s_barrier()
#define LGKM0() do { asm volatile("s_waitcnt lgkmcnt(0)" ::: "memory");        \
                     __builtin_amdgcn_sched_barrier(0); } while (0)
#define VM(n)   asm volatile("s_waitcnt vmcnt(" #n ")" ::: "memory")
#define PRIO1() __builtin_amdgcn_s_setprio(1)
#define PRIO0() __builtin_amdgcn_s_setprio(0)

__global__ __launch_bounds__(512, 2) void gemm_q32(
    const bf16_t* __restrict__ A, const bf16_t* __restrict__ Bm,
    float* __restrict__ C) {
  __shared__ __align__(16) char lds[131072];

  const int tid  = threadIdx.x;
  const int lane = tid & 63;
  const int wave = tid >> 6;
  const int wm   = wave >> 2;  // 0..1  (M half of block, 128 rows)
  const int wn   = wave & 3;   // 0..3  (N quarter of block, 64 cols)

  // T1: XCD-aware swizzle; 256 blocks % 8 == 0 -> bijective
  const int sbid = (blockIdx.x & 7) * 32 + (blockIdx.x >> 3);
  const int bm   = sbid >> 4;
  const int bn   = sbid & 15;

  const int l31 = lane & 31;
  const int hi  = lane >> 5;   // k-subslice within a K16 step

  // ds_read byte offsets in a [256][64] bf16 region (128B rows, 8 slots).
  // logical slot = kk*2 + hi; phys = slot ^ ((row>>1)&7).
  int offA[4][4], offB[2][4];
#pragma unroll
  for (int q = 0; q < 4; ++q)
#pragma unroll
    for (int kk = 0; kk < 4; ++kk) {
      const int r = wm * 128 + q * 32 + l31;
      offA[q][kk] = r * 128 + (((kk * 2 + hi) ^ ((r >> 1) & 7)) << 4);
    }
#pragma unroll
  for (int ni = 0; ni < 2; ++ni)
#pragma unroll
    for (int kk = 0; kk < 4; ++kk) {
      const int r = wn * 64 + ni * 32 + l31;
      offB[ni][kk] = r * 128 + (((kk * 2 + hi) ^ ((r >> 1) & 7)) << 4);
    }

  // staging: write-side inverse of the read swizzle
  const int srow   = tid >> 3;                              // 0..63
  const int schunk = ((tid & 7) ^ ((srow >> 1) & 7)) * 8;   // elems
  const bf16_t* Ag = A  + (size_t)bm * 256 * 4096;
  const bf16_t* Bg = Bm + (size_t)bn * 256 * 4096;

  f32x16 acc[4][2] = {};
  bf16x8 a[4], b[2][4];

  // ---- prologue: A(0), B(0), B(1); VM(4) leaves B(1)'s 4 loads in flight
  STAGE(Ag, 0,  A0_B, 0);  STAGE(Ag, 0,  A0_B, 128);
  STAGE(Bg, 0,  B0_B, 0);  STAGE(Bg, 0,  B0_B, 128);
  STAGE(Bg, 64, B1_B, 0);  STAGE(Bg, 64, B1_B, 128);
  VM(4);
  BAR();

  int kb = 0;
#pragma unroll 1
  for (int i = 0; i < 31; ++i, kb += 128) {
    // ph1: tile t q0 (B-hoist) | stage A(t+1) rows 0-127
    RDB(B0_B); RDA(A0_B, 0);
    STAGE(Ag, kb + 64, A1_B, 0);
    BAR(); LGKM0(); PRIO1(); MFMAQ(0); PRIO0(); BAR();
    // ph2: q1 | stage A(t+1) rows 128-255
    RDA(A0_B, 1);
    STAGE(Ag, kb + 64, A1_B, 128);
    BAR(); LGKM0(); PRIO1(); MFMAQ(1); PRIO0(); BAR();
    // ph3: q2 | stage B(t+2) rows 0-127   [B0 dead since ph1]
    RDA(A0_B, 2);
    STAGE(Bg, kb + 128, B0_B, 0);
    BAR(); LGKM0(); PRIO1(); MFMAQ(2); PRIO0(); BAR();
    // ph4: q3 | stage B(t+2) rows 128-255 | drain B1(prev)+A1(cur) for ph5
    RDA(A0_B, 3);
    STAGE(Bg, kb + 128, B0_B, 128);
    BAR(); LGKM0(); PRIO1(); MFMAQ(3); PRIO0(); VM(4); BAR();
    // ph5: tile t+1 q0 (B-hoist) | stage A(t+2) rows 0-127
    RDB(B1_B); RDA(A1_B, 0);
    STAGE(Ag, kb + 128, A0_B, 0);
    BAR(); LGKM0(); PRIO1(); MFMAQ(0); PRIO0(); BAR();
    // ph6: q1 | stage A(t+2) rows 128-255
    RDA(A1_B, 1);
    STAGE(Ag, kb + 128, A0_B, 128);
    BAR(); LGKM0(); PRIO1(); MFMAQ(1); PRIO0(); BAR();
    // ph7: q2 | stage B(t+3) rows 0-127   [B1 dead since ph5]
    RDA(A1_B, 2);
    STAGE(Bg, kb + 192, B1_B, 0);
    BAR(); LGKM0(); PRIO1(); MFMAQ(2); PRIO0(); BAR();
    // ph8: q3 | stage B(t+3) rows 128-255 | drain B0+A0(t+2) for next ph1
    RDA(A1_B, 3);
    STAGE(Bg, kb + 192, B1_B, 128);
    BAR(); LGKM0(); PRIO1(); MFMAQ(3); PRIO0(); VM(4); BAR();
  }

  // ---- epilogue peel (tiles 62@buf0, 63@buf1): stage only A(63); VM(0)@ep4
  RDB(B0_B); RDA(A0_B, 0);
  STAGE(Ag, 4032, A1_B, 0);
  BAR(); LGKM0(); PRIO1(); MFMAQ(0); PRIO0(); BAR();
  RDA(A0_B, 1);
  STAGE(Ag, 4032, A1_B, 128);
  BAR(); LGKM0(); PRIO1(); MFMAQ(1); PRIO0(); BAR();
  RDA(A0_B, 2);
  BAR(); LGKM0(); PRIO1(); MFMAQ(2); PRIO0(); BAR();
  RDA(A0_B, 3);
  BAR(); LGKM0(); PRIO1(); MFMAQ(3); PRIO0(); VM(0); BAR();
  RDB(B1_B); RDA(A1_B, 0);
  BAR(); LGKM0(); PRIO1(); MFMAQ(0); PRIO0(); BAR();
  RDA(A1_B, 1);
  BAR(); LGKM0(); PRIO1(); MFMAQ(1); PRIO0(); BAR();
  RDA(A1_B, 2);
  BAR(); LGKM0(); PRIO1(); MFMAQ(2); PRIO0(); BAR();
  RDA(A1_B, 3);
  LGKM0(); PRIO1(); MFMAQ(3); PRIO0();

  // ---- C write. 32x32 D layout (m74/m101 + R11-validated):
  // col = lane&31, row = (reg&3) + 8*(reg>>2) + 4*(lane>>5)
#pragma unroll
  for (int q = 0; q < 4; ++q)
#pragma unroll
    for (int ni = 0; ni < 2; ++ni) {
      const int rbase = bm * 256 + wm * 128 + q * 32 + 4 * hi;
      const int col   = bn * 256 + wn * 64 + ni * 32 + l31;
#pragma unroll
      for (int reg = 0; reg < 16; ++reg) {
        const int row = rbase + (reg & 3) + 8 * (reg >> 2);
        C[(size_t)row * 4096 + col] = acc[q][ni][reg];
      }
    }
}

// ---------------------------------------------------------------------------
extern "C" void kernel_launch(void* const* d_in, const int* in_sizes, int n_in,
                              void* d_out, int out_size, void* d_ws, size_t ws_size,
                              hipStream_t stream) {
  const float* x     = (const float*)d_in[0];
  const float* wvals = (const float*)d_in[1];
  const int*   idx   = (const int*)d_in[2];   // (2, nnz): rows then cols
  const int*   mk    = (const int*)d_in[3];   // bool -> int32 on device (R1)
  const int    nnz   = in_sizes[1];

  // ws: [0,32MB) = W bf16, [32MB,64MB) = x bf16.
  bf16_t* Wbf = (bf16_t*)d_ws;
  bf16_t* xbf = (bf16_t*)((char*)d_ws + (size_t)OUT_F * IN_F * sizeof(bf16_t));

  const size_t needed = (size_t)OUT_F * IN_F * 2 + (size_t)BATCH * IN_F * 2;
  if (ws_size < needed) return;

  // 1. zero bf16 W via DMA memset (stream-ordered before scatter)
  hipMemsetAsync(Wbf, 0, (size_t)OUT_F * IN_F * sizeof(bf16_t), stream);

  // 2. fused: atomics issued FIRST (fire-and-forget), cvt streams under them
  scatter_cvtx<<<2048, 256, 0, stream>>>(
      wvals, idx, idx + nnz, mk, (unsigned*)Wbf, nnz,
      (const float4*)x, (uint4*)xbf);

  // 3. y = x @ W^T (32x32x16 MFMA, 128B-row conflict-free LDS)
  gemm_q32<<<256, 512, 0, stream>>>(xbf, Wbf, (float*)d_out);
}

// Round 16
// 198.330 us; speedup vs baseline: 1.0314x; 1.0314x over previous
//
#include <hip/hip_runtime.h>
#include <cstdint>
#include <cstddef>

// Problem constants (SparseLinear: B=4096, IN=4096, OUT=4096, NNZ=1677722)
#define IN_F  4096
#define OUT_F 4096
#define BATCH 4096

typedef __bf16 bf16_t;
typedef __bf16 bf16x8 __attribute__((ext_vector_type(8)));
typedef float  f32x4  __attribute__((ext_vector_type(4)));

// ---------------------------------------------------------------------------
// f32 -> bf16 round-to-nearest-even (bit trick, deterministic)
// ---------------------------------------------------------------------------
__device__ __forceinline__ unsigned short f32_to_bf16_rne(float f) {
  union { float f; unsigned int u; } v;
  v.f = f;
  unsigned int u = v.u;
  return (unsigned short)((u + 0x7FFFu + ((u >> 16) & 1u)) >> 16);
}

__device__ __forceinline__ uint4 cvt8(float4 a, float4 b) {
  uint4 o;
  o.x = (unsigned)f32_to_bf16_rne(a.x) | ((unsigned)f32_to_bf16_rne(a.y) << 16);
  o.y = (unsigned)f32_to_bf16_rne(a.z) | ((unsigned)f32_to_bf16_rne(a.w) << 16);
  o.z = (unsigned)f32_to_bf16_rne(b.x) | ((unsigned)f32_to_bf16_rne(b.y) << 16);
  o.w = (unsigned)f32_to_bf16_rne(b.z) | ((unsigned)f32_to_bf16_rne(b.w) << 16);
  return o;
}

// ---------------------------------------------------------------------------
// Fused: scatter COO weights into bf16 W (packed atomic, issued FIRST so the
// fabric atomic pipe drains under the BW-bound cvt — R14: −4us) + cvt x.
// Tail is fabric-RMW-bound (~65us for 1.68M device-scope atomics; invariant
// across R6/R10/R12/R14 structures). mask is int32 on device (R1).
// Duplicates sum (coalesce semantics).
// ---------------------------------------------------------------------------
#define XUNITS ((BATCH * IN_F) / 8)   // 8-elem units of x (2097152)

__global__ __launch_bounds__(256) void scatter_cvtx(
    const float* __restrict__ w, const int* __restrict__ rows,
    const int* __restrict__ cols, const int* __restrict__ mask,
    unsigned* __restrict__ Wpk, int nnz,
    const float4* __restrict__ xin, uint4* __restrict__ xbf) {
  const int total = XUNITS + nnz;
  for (int u = blockIdx.x * 256 + threadIdx.x; u < total;
       u += gridDim.x * 256) {
    if (u < nnz) {                      // atomics first (fire-and-forget)
      if (mask[u] != 0) {
        const unsigned h = f32_to_bf16_rne(w[u]);
        const size_t e = (size_t)rows[u] * IN_F + cols[u];
        const unsigned data = (e & 1) ? (h << 16) : h;
        unsigned* p = Wpk + (e >> 1);
        asm volatile("global_atomic_pk_add_bf16 %0, %1, off"
                     :: "v"(p), "v"(data) : "memory");
      }
    } else {                            // BW-bound cvt streams under them
      const int i = u - nnz;
      xbf[i] = cvt8(xin[2 * i], xin[2 * i + 1]);
    }
  }
}

// ---------------------------------------------------------------------------
// FINAL: R13 quadrant/B-hoist 256x256 bf16 GEMM, C = A @ Bm^T.
// 116.0us, 1180 TF, MfmaUtil ~50, bank conflicts 0. Converged: six variants
// (R4 8-phase, R5 deep-vmcnt, R6 4-phase, R8 readahead, R13 quadrant,
// R15 32x32x16/128B-rows) all plateau at 116-118us. Accounting: per K64
// tile per CU, LDS-read term (192 x b128 ~ 2304cy, CU-shared/saturated)
// exceeds the MFMA term (~155cy/SIMD/phase) and they run near-serial under
// 1-block/CU barrier lockstep. R11 (128x128/wave to cut LDS bytes) spills.
// Tail: fabric-RMW-bound. Remaining headroom is sub-source scheduling.
// ---------------------------------------------------------------------------
#define A0_B 0
#define B0_B 32768
#define A1_B 65536
#define B1_B 98304
#define HALF 16384

#define STAGE(Xg, kpos, ldsbase) do {                                          \
  __builtin_amdgcn_global_load_lds(                                            \
    (const __attribute__((address_space(1))) void*)((Xg) + (size_t)srow * 4096 + (kpos) + schunk), \
    (__attribute__((address_space(3))) void*)(lds + (ldsbase) + tid * 16), 16, 0, 0); \
  __builtin_amdgcn_global_load_lds(                                            \
    (const __attribute__((address_space(1))) void*)((Xg) + (size_t)(srow + 128) * 4096 + (kpos) + schunk), \
    (__attribute__((address_space(3))) void*)(lds + (ldsbase) + 8192 + tid * 16), 16, 0, 0); \
} while (0)

// B for the whole K64 tile: 4 N-frags x 2 k-halves (8 x ds_read_b128)
#define RDB(base) do {                                                         \
  _Pragma("unroll")                                                            \
  for (int ni = 0; ni < 4; ++ni)                                               \
    _Pragma("unroll")                                                          \
    for (int kk = 0; kk < 2; ++kk)                                             \
      b[ni][kk] = *(const bf16x8*)(lds + (base) + kk * HALF + offB[ni]);       \
} while (0)

// A for one quadrant: 2 M-frags x 2 k-halves (4 x ds_read_b128)
#define RDA(base, q) do {                                                      \
  _Pragma("unroll")                                                            \
  for (int mi = 0; mi < 2; ++mi)                                               \
    _Pragma("unroll")                                                          \
    for (int kk = 0; kk < 2; ++kk)                                             \
      a[mi][kk] = *(const bf16x8*)(lds + (base) + kk * HALF + offA[q][mi]);    \
} while (0)

// One quadrant x K64: 2M x 4N x 2K = 16 MFMA (all indices compile-time)
#define MFMAQ(q) do {                                                          \
  _Pragma("unroll")                                                            \
  for (int mi = 0; mi < 2; ++mi)                                               \
    _Pragma("unroll")                                                          \
    for (int ni = 0; ni < 4; ++ni)                                             \
      _Pragma("unroll")                                                        \
      for (int kk = 0; kk < 2; ++kk)                                           \
        acc[2 * (q) + mi][ni] = __builtin_amdgcn_mfma_f32_16x16x32_bf16(       \
            a[mi][kk], b[ni][kk], acc[2 * (q) + mi][ni], 0, 0, 0);             \
} while (0)

#define BAR()   __builtin_amdgcn_s_barrier()
#define LGKM0() do { asm volatile("s_waitcnt lgkmcnt(0)" ::: "memory");        \
                     __builtin_amdgcn_sched_barrier(0); } while (0)
#define VM(n)   asm volatile("s_waitcnt vmcnt(" #n ")" ::: "memory")
#define PRIO1() __builtin_amdgcn_s_setprio(1)
#define PRIO0() __builtin_amdgcn_s_setprio(0)

__global__ __launch_bounds__(512, 2) void gemm_q(
    const bf16_t* __restrict__ A, const bf16_t* __restrict__ Bm,
    float* __restrict__ C) {
  __shared__ __align__(16) char lds[131072];

  const int tid  = threadIdx.x;
  const int lane = tid & 63;
  const int wave = tid >> 6;
  const int wm   = wave >> 2;  // 0..1  (M half of block)
  const int wn   = wave & 3;   // 0..3  (N quarter of block)

  // T1: XCD-aware swizzle; 256 blocks % 8 == 0 -> bijective
  const int sbid = (blockIdx.x & 7) * 32 + (blockIdx.x >> 3);
  const int bm   = sbid >> 4;
  const int bn   = sbid & 15;

  const int frow = lane & 15;
  const int c16  = (lane >> 4) * 16;  // 16B chunk within 64B row

  // ds_read byte offsets within a ks-half [256][32] region (R4-verified
  // decorrelated swizzle: slot ^ ((row>>1)&3), 0 conflicts)
  int offA[4][2], offB[4];
#pragma unroll
  for (int q = 0; q < 4; ++q)
#pragma unroll
    for (int mi = 0; mi < 2; ++mi) {
      int r = wm * 128 + q * 32 + mi * 16 + frow;
      offA[q][mi] = r * 64 + (c16 ^ (((r >> 1) & 3) << 4));
    }
#pragma unroll
  for (int ni = 0; ni < 4; ++ni) {
    int r = wn * 64 + ni * 16 + frow;
    offB[ni] = r * 64 + (c16 ^ (((r >> 1) & 3) << 4));
  }

  // staging: write-side inverse of the read swizzle ((srow+128) keeps the
  // same ((row>>1)&3): bit7 is stripped by &3)
  const int srow   = tid >> 2;
  const int schunk = ((tid & 3) ^ ((srow >> 1) & 3)) * 8;
  const bf16_t* Ag = A  + (size_t)bm * 256 * 4096;
  const bf16_t* Bg = Bm + (size_t)bn * 256 * 4096;

  f32x4 acc[8][4] = {};
  bf16x8 a[2][2], b[4][2];

  // ---- prologue: A(0), B(0), B(1); VM(4) leaves B(1) in flight
  STAGE(Ag, 0,  A0_B);
  STAGE(Ag, 32, A0_B + HALF);
  STAGE(Bg, 0,  B0_B);
  STAGE(Bg, 32, B0_B + HALF);
  STAGE(Bg, 64, B1_B);
  STAGE(Bg, 96, B1_B + HALF);
  VM(4);
  BAR();

  int kb = 0;
#pragma unroll 1
  for (int i = 0; i < 31; ++i, kb += 128) {
    // ph1: tile t q0 (B hoist: read all B(t) + A q0) | stage A(t+1)ks0
    RDB(B0_B); RDA(A0_B, 0);
    STAGE(Ag, kb + 64, A1_B);
    BAR(); LGKM0(); PRIO1(); MFMAQ(0); PRIO0(); BAR();
    // ph2: tile t q1 | stage A(t+1)ks1
    RDA(A0_B, 1);
    STAGE(Ag, kb + 96, A1_B + HALF);
    BAR(); LGKM0(); PRIO1(); MFMAQ(1); PRIO0(); BAR();
    // ph3: tile t q2 | stage B(t+2)ks0   [B0 dead since ph1]
    RDA(A0_B, 2);
    STAGE(Bg, kb + 128, B0_B);
    BAR(); LGKM0(); PRIO1(); MFMAQ(2); PRIO0(); BAR();
    // ph4: tile t q3 | stage B(t+2)ks1 | drain B1(prev)+A1(cur) for ph5
    RDA(A0_B, 3);
    STAGE(Bg, kb + 160, B0_B + HALF);
    BAR(); LGKM0(); PRIO1(); MFMAQ(3); PRIO0(); VM(4); BAR();
    // ph5: tile t+1 q0 (read all B(t+1) + A q0) | stage A(t+2)ks0
    RDB(B1_B); RDA(A1_B, 0);
    STAGE(Ag, kb + 128, A0_B);
    BAR(); LGKM0(); PRIO1(); MFMAQ(0); PRIO0(); BAR();
    // ph6: tile t+1 q1 | stage A(t+2)ks1
    RDA(A1_B, 1);
    STAGE(Ag, kb + 160, A0_B + HALF);
    BAR(); LGKM0(); PRIO1(); MFMAQ(1); PRIO0(); BAR();
    // ph7: tile t+1 q2 | stage B(t+3)ks0   [B1 dead since ph5]
    RDA(A1_B, 2);
    STAGE(Bg, kb + 192, B1_B);
    BAR(); LGKM0(); PRIO1(); MFMAQ(2); PRIO0(); BAR();
    // ph8: tile t+1 q3 | stage B(t+3)ks1 | drain B0+A0(t+2) for next ph1
    RDA(A1_B, 3);
    STAGE(Bg, kb + 224, B1_B + HALF);
    BAR(); LGKM0(); PRIO1(); MFMAQ(3); PRIO0(); VM(4); BAR();
  }

  // ---- epilogue peel (t=62,63; kb == 3968): stages only A(63), VM(0)@ph4
  RDB(B0_B); RDA(A0_B, 0);
  STAGE(Ag, 4032, A1_B);                     // A(63)ks0
  BAR(); LGKM0(); PRIO1(); MFMAQ(0); PRIO0(); BAR();
  RDA(A0_B, 1);
  STAGE(Ag, 4064, A1_B + HALF);              // A(63)ks1
  BAR(); LGKM0(); PRIO1(); MFMAQ(1); PRIO0(); BAR();
  RDA(A0_B, 2);
  BAR(); LGKM0(); PRIO1(); MFMAQ(2); PRIO0(); BAR();
  RDA(A0_B, 3);
  BAR(); LGKM0(); PRIO1(); MFMAQ(3); PRIO0(); VM(0); BAR();
  RDB(B1_B); RDA(A1_B, 0);
  BAR(); LGKM0(); PRIO1(); MFMAQ(0); PRIO0(); BAR();
  RDA(A1_B, 1);
  BAR(); LGKM0(); PRIO1(); MFMAQ(1); PRIO0(); BAR();
  RDA(A1_B, 2);
  BAR(); LGKM0(); PRIO1(); MFMAQ(2); PRIO0(); BAR();
  RDA(A1_B, 3);
  LGKM0(); PRIO1(); MFMAQ(3); PRIO0();

  // ---- C write (D layout: col = lane&15, row = (lane>>4)*4 + jj);
  // acc[m] <-> M-row block wm*128 + m*16 (m = 2q+mi).
#pragma unroll
  for (int m = 0; m < 8; ++m)
#pragma unroll
    for (int ni = 0; ni < 4; ++ni) {
      const int row = bm * 256 + wm * 128 + m * 16 + (lane >> 4) * 4;
      const int col = bn * 256 + wn * 64 + ni * 16 + frow;
#pragma unroll
      for (int jj = 0; jj < 4; ++jj)
        C[(size_t)(row + jj) * 4096 + col] = acc[m][ni][jj];
    }
}

// ---------------------------------------------------------------------------
extern "C" void kernel_launch(void* const* d_in, const int* in_sizes, int n_in,
                              void* d_out, int out_size, void* d_ws, size_t ws_size,
                              hipStream_t stream) {
  const float* x     = (const float*)d_in[0];
  const float* wvals = (const float*)d_in[1];
  const int*   idx   = (const int*)d_in[2];   // (2, nnz): rows then cols
  const int*   mk    = (const int*)d_in[3];   // bool -> int32 on device (R1)
  const int    nnz   = in_sizes[1];

  // ws: [0,32MB) = W bf16, [32MB,64MB) = x bf16.
  bf16_t* Wbf = (bf16_t*)d_ws;
  bf16_t* xbf = (bf16_t*)((char*)d_ws + (size_t)OUT_F * IN_F * sizeof(bf16_t));

  const size_t needed = (size_t)OUT_F * IN_F * 2 + (size_t)BATCH * IN_F * 2;
  if (ws_size < needed) return;

  // 1. zero bf16 W via DMA memset (stream-ordered before scatter)
  hipMemsetAsync(Wbf, 0, (size_t)OUT_F * IN_F * sizeof(bf16_t), stream);

  // 2. fused: atomics issued FIRST (fire-and-forget), cvt streams under them
  scatter_cvtx<<<2048, 256, 0, stream>>>(
      wvals, idx, idx + nnz, mk, (unsigned*)Wbf, nnz,
      (const float4*)x, (uint4*)xbf);

  // 3. y = x @ W^T (frozen R13 quadrant/B-hoist schedule)
  gemm_q<<<256, 512, 0, stream>>>(xbf, Wbf, (float*)d_out);
}